// Round 8
// baseline (148.096 us; speedup 1.0000x reference)
//
#include <hip/hip_runtime.h>

typedef __attribute__((ext_vector_type(8))) short short8;
typedef __attribute__((ext_vector_type(4))) float f32x4;

#define GROUP_ELEMS 2097152     // 2 channels * 64*128*128
#define NBLK 64

__device__ inline short f2bf(float f) {
  unsigned u = __builtin_bit_cast(unsigned, f);
  unsigned r = (u + 0x7FFFu + ((u >> 16) & 1u)) >> 16;
  return (short)r;
}

__device__ inline void gload_lds16(const void* g, void* l) {
  __builtin_amdgcn_global_load_lds(
      (const __attribute__((address_space(1))) unsigned int*)g,
      (__attribute__((address_space(3))) unsigned int*)l, 16, 0, 0);
}

__global__ __launch_bounds__(256) void k1_partials(const float* __restrict__ x,
                                                   float2* __restrict__ partials) {
  int group = blockIdx.x >> 6;
  int blk = blockIdx.x & 63;
  const float4* p = (const float4*)(x + (size_t)group * GROUP_ELEMS + (size_t)blk * 32768);
  float sum = 0.f, sq = 0.f;
  for (int i = threadIdx.x; i < 8192; i += 256) {
    float4 v = p[i];
    sum += v.x + v.y + v.z + v.w;
    sq  += v.x*v.x + v.y*v.y + v.z*v.z + v.w*v.w;
  }
  for (int off = 32; off; off >>= 1) {
    sum += __shfl_down(sum, off, 64);
    sq  += __shfl_down(sq,  off, 64);
  }
  __shared__ float2 sw[4];
  int lane = threadIdx.x & 63, wid = threadIdx.x >> 6;
  if (lane == 0) sw[wid] = make_float2(sum, sq);
  __syncthreads();
  if (threadIdx.x == 0) {
    float s = 0.f, q = 0.f;
    for (int j = 0; j < 4; ++j) { s += sw[j].x; q += sw[j].y; }
    partials[blockIdx.x] = make_float2(s, q);
  }
}

// merged prep: group stats + hist zero + dummy zero + plane-major conv-weight
// repack. frag f = kd*5 + c (kd=0..2, c=0..4); tap = 2c + (lane>>5) (9 = pad):
// fbw2[(f*64+lane)*8+j] = bf16(W[oc=lane&15][ic=((lane>>4)&1)*8+j][kd][tap/3][tap%3])
__global__ void k2_prep(const float2* __restrict__ partials, const float* __restrict__ wgt,
                        float2* __restrict__ stats, int* __restrict__ hist,
                        unsigned short* __restrict__ fbw2, unsigned int* __restrict__ dummy) {
  int t = threadIdx.x;             // 1024 threads; 960 = 15 frags * 64 lanes
  if (t < 16) {
    float s = 0.f, q = 0.f;
    for (int j = 0; j < NBLK; ++j) { float2 p = partials[t * NBLK + j]; s += p.x; q += p.y; }
    float mean = s / (float)GROUP_ELEMS;
    float var  = q / (float)GROUP_ELEMS - mean * mean;
    stats[t] = make_float2(mean, rsqrtf(var + 1e-5f));
  }
  if (t < 21) hist[t] = 0;
  if (t < 960) {
    int f = t >> 6, lane = t & 63;
    int kd = f / 5, c = f - kd * 5;
    int m = lane & 15, g = lane >> 4;
    int icb = (g & 1) * 8, g2 = g >> 1;
    int tap = 2 * c + g2;          // 0..9
    short8 v;
    #pragma unroll
    for (int j = 0; j < 8; ++j)
      v[j] = (tap <= 8) ? f2bf(wgt[m * 432 + (icb + j) * 27 + kd * 9 + tap]) : (short)0;
    *(short8*)(fbw2 + t * 8) = v;
  }
  if (t >= 960 && t < 976) dummy[t - 960] = 0;
}

// GroupNorm+ReLU+hist+threshold — scalar version (measured best).
// Thread per (b, hw, channel-pair): 1024 blocks x 256 thr.
__global__ __launch_bounds__(256) void k3_norm_thresh_hist(
    const float* __restrict__ x, const float* __restrict__ gw, const float* __restrict__ gb,
    const float* __restrict__ thrp, const float2* __restrict__ stats,
    unsigned short* __restrict__ z, int* __restrict__ hist) {
  __shared__ int sh[21];
  int t = threadIdx.x;
  if (t < 21) sh[t] = 0;
  __syncthreads();
  int hwl = t & 31, cp = t >> 5;
  int b = blockIdx.x >> 9;
  int hw = (blockIdx.x & 511) * 32 + hwl;
  int c0 = cp * 2, c1 = c0 + 1;
  float2 st = stats[b * 8 + cp];
  float A0 = gw[c0] * st.y, B0 = gb[c0] - st.x * A0;
  float A1 = gw[c1] * st.y, B1 = gb[c1] - st.x * A1;
  float thr = thrp[0];
  const float* px0 = x + (size_t)(b * 16 + c0) * 1048576 + hw;
  const float* px1 = x + (size_t)(b * 16 + c1) * 1048576 + hw;
  unsigned* pz = (unsigned*)(z + ((size_t)b * 64 * 16384 + hw) * 16 + c0);
  int c10 = 0, c11 = 0, c12 = 0;
  float xv0 = px0[0], xv1 = px1[0];
  float yp0 = 0.f, yp1 = 0.f;
  for (int d = 0; d < 64; ++d) {
    float n0 = 0.f, n1 = 0.f;
    if (d < 63) { n0 = px0[(d + 1) * 16384]; n1 = px1[(d + 1) * 16384]; }
    float y0 = fmaxf(fmaf(xv0, A0, B0), 0.f);
    float y1 = fmaxf(fmaf(xv1, A1, B1), 0.f);
    float v0 = ceilf(0.5f * y0);
    if (v0 == 0.f) c10++; else if (v0 == 1.f) c11++; else if (v0 == 2.f) c12++;
    else if (v0 <= 10.f) atomicAdd(&sh[(int)v0 + 10], 1);
    float v1 = ceilf(0.5f * y1);
    if (v1 == 0.f) c10++; else if (v1 == 1.f) c11++; else if (v1 == 2.f) c12++;
    else if (v1 <= 10.f) atomicAdd(&sh[(int)v1 + 10], 1);
    float z0, z1;
    if (d == 0) { z0 = y0; z1 = y1; }
    else {
      float dd0 = (y0 - yp0) / thr;
      z0 = (fabsf(dd0) > 1.f) ? fmaf(dd0, thr, yp0) : yp0;
      float dd1 = (y1 - yp1) / thr;
      z1 = (fabsf(dd1) > 1.f) ? fmaf(dd1, thr, yp1) : yp1;
    }
    unsigned u = (unsigned)(unsigned short)f2bf(z0) | ((unsigned)(unsigned short)f2bf(z1) << 16);
    pz[d * 131072] = u;
    yp0 = y0; yp1 = y1;
    xv0 = n0; xv1 = n1;
  }
  atomicAdd(&sh[10], c10);
  atomicAdd(&sh[11], c11);
  atomicAdd(&sh[12], c12);
  __syncthreads();
  if (t < 21) atomicAdd(&hist[t], sh[t]);
}

// MFMA implicit-GEMM conv, plane-major 512-thr (R7 best) + T2 BANK SWIZZLE.
// A-reads are ds_read_b128 at lane-stride 32 B: per 16-lane quarter-wave phase
// the words land on only 4 of 8 bank-quads (4 words/bank vs 2 free) -> ~2x on
// the LDS pipe. Fix (both-sides, m173-pattern): LDS stays LINEAR (required by
// global_load_lds); the GLOBAL SOURCE granule is permuted at staging
// (g_src = gi ^ ((gi>>3)&1), intra-plane, slot-independent) and the READ
// applies the same involution on the intra-plane ushort offset
// (o ^= ((o>>6)&1)<<3). After the swizzle lanes m=0-3 / 4-7 hit complementary
// bank-quads -> all 32 banks x 2 words = conflict-free, for every tap and both
// icb halves. Pure data permutation: absmax must stay bit-identical.
#define DT 8
#define PLANE 5440          // 10*34*16 ushorts = 10,880 B per plane slot
__global__ __launch_bounds__(512, 4) void k4_conv(const unsigned short* __restrict__ z,
                                                  const unsigned short* __restrict__ fbw2,
                                                  const char* __restrict__ dummyc,
                                                  const int* __restrict__ hist,
                                                  float* __restrict__ out) {
  __shared__ unsigned short lz[2 * PLANE];   // 21,760 B
  const int t = threadIdx.x;
  if (blockIdx.x == 0 && blockIdx.y == 0 && blockIdx.z == 0 && t < 21)
    out[33554432u + t] = (float)hist[t] * (100.0f / 33554432.0f);
  const int lane = t & 63, wid = t >> 6;     // 8 waves
  const int b = blockIdx.z;
  const int d0 = blockIdx.y * DT;
  const int h0 = (blockIdx.x >> 2) * 8, w0 = (blockIdx.x & 3) * 32;
  const int m = lane & 15, g = lane >> 4;
  const int icb = (g & 1) * 8, g2 = g >> 1;

  // weights: 15 B-fragments (kd*5 + c), register-resident (60 VGPR)
  short8 fb2[15];
  #pragma unroll
  for (int f = 0; f < 15; ++f)
    fb2[f] = *(const short8*)(fbw2 + (f * 64 + lane) * 8);

  // per-lane A-read tap offsets (ushort units) for c = 0..4
  int tco[5];
  #pragma unroll
  for (int c = 0; c < 5; ++c) {
    int tap = 2 * c + g2; if (tap > 8) tap = 8;
    tco[c] = ((tap / 3) * 34 + (tap % 3)) * 16;
  }

  const char* zbc = (const char*)(z + (size_t)b * 16777216);   // bytes base

  // staging: 680 granules/plane. chunk A: granule = t (waves 0-7, 512).
  // chunk B: wid0 -> 512+, wid1 -> 576+, wid2 -> 616+ (616-639 double-written
  // with identical data); waves 3-7 idle on chunk B.
  // SWIZZLE: the global source coords come from g_src = gi ^ ((gi>>3)&1)
  // (intra-plane granule involution); the LDS dest stays at gi (linear DMA).
  const int cbA = wid * 64;
  const int cbB = (wid == 0) ? 512 : (wid == 1) ? 576 : 616;
  const bool hasB = (wid < 3);
  long long hobA, hobB; bool hvA, hvB;
  {
    int gi, gsw, r, rem, s, ig, hg, wg;
    gi = cbA + lane; gsw = gi ^ ((gi >> 3) & 1);
    r = gsw / 68; rem = gsw - r * 68; s = rem >> 1; ig = rem & 1;
    hg = h0 - 1 + r; wg = w0 - 1 + s;
    hvA = ((unsigned)hg < 128u) && ((unsigned)wg < 128u);
    hobA = ((long long)(hg * 128 + wg) * 16 + ig * 8) * 2;
    gi = cbB + lane; gsw = gi ^ ((gi >> 3) & 1);
    r = gsw / 68; rem = gsw - r * 68; s = rem >> 1; ig = rem & 1;
    hg = h0 - 1 + r; wg = w0 - 1 + s;
    hvB = ((unsigned)hg < 128u) && ((unsigned)wg < 128u);
    hobB = ((long long)(hg * 128 + wg) * 16 + ig * 8) * 2;
  }

  const f32x4 fzero = {0.f, 0.f, 0.f, 0.f};
  f32x4 A0[2], A1[2], A2[2];
  #pragma unroll
  for (int q = 0; q < 2; ++q) { A0[q] = fzero; A1[q] = fzero; A2[q] = fzero; }

  // prologue: stage plane 0 (global d = d0-1) into slot 0
  {
    const int dg = d0 - 1;
    const long long dgo = (long long)dg * 524288;
    const bool pd = (unsigned)dg < 64u;
    gload_lds16((pd && hvA) ? zbc + dgo + hobA : dummyc, &lz[cbA * 8]);
    if (hasB)
      gload_lds16((pd && hvB) ? zbc + dgo + hobB : dummyc, &lz[cbB * 8]);
  }
  __syncthreads();

  // BODY(ph): issue loads for plane ph+1 -> slot (ph+1)&1; compute plane ph
  // from slot ph&1 (j2 -> AN [kd=0], j1 -> AM [kd=1], j0 -> AS [kd=2]);
  // store AS (dout = d0+ph-2); barrier. A-read offset: intra-plane o gets the
  // same XOR involution as the staged source; su added after.
#define BODY(PH, AS, AM, AN, DOJ2, DOJ1, DOJ0, DOLOAD, DOSTORE)                         \
  {                                                                                     \
    const int ph_ = (PH);                                                               \
    if (DOLOAD) {                                                                       \
      const int dg = d0 + ph_;                                                          \
      const long long dgo = (long long)dg * 524288;                                     \
      const bool pd = (unsigned)dg < 64u;                                               \
      const unsigned sl = ((unsigned)(ph_ + 1) & 1u) * PLANE;                           \
      gload_lds16((pd && hvA) ? zbc + dgo + hobA : dummyc, &lz[sl + cbA * 8]);          \
      if (hasB)                                                                         \
        gload_lds16((pd && hvB) ? zbc + dgo + hobB : dummyc, &lz[sl + cbB * 8]);        \
    }                                                                                   \
    const unsigned su = ((unsigned)ph_ & 1u) * PLANE;                                   \
    __builtin_amdgcn_s_setprio(1);                                                      \
    _Pragma("unroll")                                                                   \
    for (int q = 0; q < 2; ++q) {                                                       \
      const int hl = wid, wt = q;                                                       \
      const int qb = (hl * 34 + wt * 16 + m) * 16 + icb;                                \
      _Pragma("unroll")                                                                 \
      for (int c = 0; c < 5; ++c) {                                                     \
        int o = qb + tco[c];                                                            \
        o ^= ((o >> 6) & 1) << 3;                                                       \
        short8 a = *(const short8*)(&lz[su + o]);                                       \
        if (DOJ2) AN[q] = __builtin_amdgcn_mfma_f32_16x16x32_bf16(a, fb2[c], AN[q], 0, 0, 0);      \
        if (DOJ1) AM[q] = __builtin_amdgcn_mfma_f32_16x16x32_bf16(a, fb2[5 + c], AM[q], 0, 0, 0);  \
        if (DOJ0) AS[q] = __builtin_amdgcn_mfma_f32_16x16x32_bf16(a, fb2[10 + c], AS[q], 0, 0, 0); \
      }                                                                                 \
    }                                                                                   \
    __builtin_amdgcn_s_setprio(0);                                                      \
    if (DOSTORE) {                                                                      \
      const int dd = d0 + ph_ - 2;                                                      \
      _Pragma("unroll")                                                                 \
      for (int q = 0; q < 2; ++q) {                                                     \
        const int hl = wid, wt = q;                                                     \
        float* op = out + (((size_t)(b * 16 + m) * 64 + dd) * 128 + (h0 + hl)) * 128    \
                    + w0 + wt * 16 + g * 4;                                             \
        *(float4*)op = make_float4(AS[q][0], AS[q][1], AS[q][2], AS[q][3]);             \
        AS[q] = fzero;                                                                  \
      }                                                                                 \
    }                                                                                   \
    __syncthreads();                                                                    \
  }

  // peel: planes 0,1 skip j's that would target out-of-block depths
  BODY(0, A1, A2, A0, 1, 0, 0, 1, 0)
  BODY(1, A2, A0, A1, 1, 1, 0, 1, 0)
  BODY(2, A0, A1, A2, 1, 1, 1, 1, 1)
  #pragma unroll 1
  for (int pp = 3; pp <= 6; pp += 3) {
    BODY(pp,     A1, A2, A0, 1, 1, 1, 1, 1)
    BODY(pp + 1, A2, A0, A1, 1, 1, 1, 1, 1)
    BODY(pp + 2, A0, A1, A2, 1, 1, 1, 1, 1)
  }
  // tail: plane 9 only finishes dout d0+7 (j0); no further loads
  BODY(9, A1, A2, A0, 0, 0, 1, 0, 1)
#undef BODY
}

extern "C" void kernel_launch(void* const* d_in, const int* in_sizes, int n_in,
                              void* d_out, int out_size, void* d_ws, size_t ws_size,
                              hipStream_t stream) {
  (void)in_sizes; (void)n_in; (void)out_size; (void)ws_size;
  const float* x   = (const float*)d_in[0];
  const float* gw  = (const float*)d_in[1];
  const float* gb  = (const float*)d_in[2];
  const float* thr = (const float*)d_in[3];
  const float* cw  = (const float*)d_in[4];
  float* out = (float*)d_out;

  char* ws = (char*)d_ws;
  unsigned short* z = (unsigned short*)ws;                               // 64 MiB bf16
  float2* partials  = (float2*)(ws + (size_t)67108864);                  // 8 KiB
  float2* stats     = (float2*)(ws + (size_t)67108864 + 8192);           // 128 B
  int*    hist      = (int*)  (ws + (size_t)67108864 + 8192 + 128);      // 84 B
  unsigned int* dummy = (unsigned int*)(ws + (size_t)67108864 + 8448);   // 64 B zeros
  unsigned short* fbw2 = (unsigned short*)(ws + (size_t)67108864 + 16384); // 15,360 B

  k1_partials<<<1024, 256, 0, stream>>>(x, partials);
  k2_prep<<<1, 1024, 0, stream>>>(partials, cw, stats, hist, fbw2, dummy);
  k3_norm_thresh_hist<<<1024, 256, 0, stream>>>(x, gw, gb, thr, stats, z, hist);
  k4_conv<<<dim3(64, 8, 2), 512, 0, stream>>>(z, fbw2, (const char*)dummy, hist, out);
}

// Round 9
// 133.552 us; speedup vs baseline: 1.1089x; 1.1089x over previous
//
#include <hip/hip_runtime.h>

typedef __attribute__((ext_vector_type(8))) short short8;
typedef __attribute__((ext_vector_type(4))) float f32x4;

#define GROUP_ELEMS 2097152     // 2 channels * 64*128*128
#define NBLK 64

__device__ inline short f2bf(float f) {
  unsigned u = __builtin_bit_cast(unsigned, f);
  unsigned r = (u + 0x7FFFu + ((u >> 16) & 1u)) >> 16;
  return (short)r;
}

__device__ inline void gload_lds16(const void* g, void* l) {
  __builtin_amdgcn_global_load_lds(
      (const __attribute__((address_space(1))) unsigned int*)g,
      (__attribute__((address_space(3))) unsigned int*)l, 16, 0, 0);
}

__global__ __launch_bounds__(256) void k1_partials(const float* __restrict__ x,
                                                   float2* __restrict__ partials) {
  int group = blockIdx.x >> 6;
  int blk = blockIdx.x & 63;
  const float4* p = (const float4*)(x + (size_t)group * GROUP_ELEMS + (size_t)blk * 32768);
  float sum = 0.f, sq = 0.f;
  for (int i = threadIdx.x; i < 8192; i += 256) {
    float4 v = p[i];
    sum += v.x + v.y + v.z + v.w;
    sq  += v.x*v.x + v.y*v.y + v.z*v.z + v.w*v.w;
  }
  for (int off = 32; off; off >>= 1) {
    sum += __shfl_down(sum, off, 64);
    sq  += __shfl_down(sq,  off, 64);
  }
  __shared__ float2 sw[4];
  int lane = threadIdx.x & 63, wid = threadIdx.x >> 6;
  if (lane == 0) sw[wid] = make_float2(sum, sq);
  __syncthreads();
  if (threadIdx.x == 0) {
    float s = 0.f, q = 0.f;
    for (int j = 0; j < 4; ++j) { s += sw[j].x; q += sw[j].y; }
    partials[blockIdx.x] = make_float2(s, q);
  }
}

// merged prep: group stats + hist zero + dummy zero + plane-major conv-weight
// repack. frag f = kd*5 + c (kd=0..2, c=0..4); tap = 2c + (lane>>5) (9 = pad):
// fbw2[(f*64+lane)*8+j] = bf16(W[oc=lane&15][ic=((lane>>4)&1)*8+j][kd][tap/3][tap%3])
__global__ void k2_prep(const float2* __restrict__ partials, const float* __restrict__ wgt,
                        float2* __restrict__ stats, int* __restrict__ hist,
                        unsigned short* __restrict__ fbw2, unsigned int* __restrict__ dummy) {
  int t = threadIdx.x;             // 1024 threads; 960 = 15 frags * 64 lanes
  if (t < 16) {
    float s = 0.f, q = 0.f;
    for (int j = 0; j < NBLK; ++j) { float2 p = partials[t * NBLK + j]; s += p.x; q += p.y; }
    float mean = s / (float)GROUP_ELEMS;
    float var  = q / (float)GROUP_ELEMS - mean * mean;
    stats[t] = make_float2(mean, rsqrtf(var + 1e-5f));
  }
  if (t < 21) hist[t] = 0;
  if (t < 960) {
    int f = t >> 6, lane = t & 63;
    int kd = f / 5, c = f - kd * 5;
    int m = lane & 15, g = lane >> 4;
    int icb = (g & 1) * 8, g2 = g >> 1;
    int tap = 2 * c + g2;          // 0..9
    short8 v;
    #pragma unroll
    for (int j = 0; j < 8; ++j)
      v[j] = (tap <= 8) ? f2bf(wgt[m * 432 + (icb + j) * 27 + kd * 9 + tap]) : (short)0;
    *(short8*)(fbw2 + t * 8) = v;
  }
  if (t >= 960 && t < 976) dummy[t - 960] = 0;
}

// GroupNorm+ReLU+hist+threshold — scalar structure (measured best), two
// targeted edits vs R7: (1) threshold recurrence div removed via identity
// fmaf((y-yp)/thr, thr, yp) == y up to 1 ulp -> z = (|y-yp|>thr) ? y : yp
// (tolerance absorbs the ulp; halves per-d VALU); (2) 2-deep x prefetch
// (1-deep barely covered ~900cy HBM latency at 4 waves/SIMD).
__global__ __launch_bounds__(256) void k3_norm_thresh_hist(
    const float* __restrict__ x, const float* __restrict__ gw, const float* __restrict__ gb,
    const float* __restrict__ thrp, const float2* __restrict__ stats,
    unsigned short* __restrict__ z, int* __restrict__ hist) {
  __shared__ int sh[21];
  int t = threadIdx.x;
  if (t < 21) sh[t] = 0;
  __syncthreads();
  int hwl = t & 31, cp = t >> 5;
  int b = blockIdx.x >> 9;
  int hw = (blockIdx.x & 511) * 32 + hwl;
  int c0 = cp * 2, c1 = c0 + 1;
  float2 st = stats[b * 8 + cp];
  float A0 = gw[c0] * st.y, B0 = gb[c0] - st.x * A0;
  float A1 = gw[c1] * st.y, B1 = gb[c1] - st.x * A1;
  float thr = thrp[0];
  const float* px0 = x + (size_t)(b * 16 + c0) * 1048576 + hw;
  const float* px1 = x + (size_t)(b * 16 + c1) * 1048576 + hw;
  unsigned* pz = (unsigned*)(z + ((size_t)b * 64 * 16384 + hw) * 16 + c0);
  int c10 = 0, c11 = 0, c12 = 0;
  float xv0 = px0[0], xv1 = px1[0];
  float xm0 = px0[16384], xm1 = px1[16384];
  float yp0 = 0.f, yp1 = 0.f;
  for (int d = 0; d < 64; ++d) {
    float n0 = 0.f, n1 = 0.f;
    if (d < 62) { n0 = px0[(d + 2) * 16384]; n1 = px1[(d + 2) * 16384]; }
    float y0 = fmaxf(fmaf(xv0, A0, B0), 0.f);
    float y1 = fmaxf(fmaf(xv1, A1, B1), 0.f);
    float v0 = ceilf(0.5f * y0);
    if (v0 == 0.f) c10++; else if (v0 == 1.f) c11++; else if (v0 == 2.f) c12++;
    else if (v0 <= 10.f) atomicAdd(&sh[(int)v0 + 10], 1);
    float v1 = ceilf(0.5f * y1);
    if (v1 == 0.f) c10++; else if (v1 == 1.f) c11++; else if (v1 == 2.f) c12++;
    else if (v1 <= 10.f) atomicAdd(&sh[(int)v1 + 10], 1);
    float z0, z1;
    if (d == 0) { z0 = y0; z1 = y1; }
    else {
      z0 = (fabsf(y0 - yp0) > thr) ? y0 : yp0;
      z1 = (fabsf(y1 - yp1) > thr) ? y1 : yp1;
    }
    unsigned u = (unsigned)(unsigned short)f2bf(z0) | ((unsigned)(unsigned short)f2bf(z1) << 16);
    pz[d * 131072] = u;
    yp0 = y0; yp1 = y1;
    xv0 = xm0; xv1 = xm1;
    xm0 = n0; xm1 = n1;
  }
  atomicAdd(&sh[10], c10);
  atomicAdd(&sh[11], c11);
  atomicAdd(&sh[12], c12);
  __syncthreads();
  if (t < 21) atomicAdd(&hist[t], sh[t]);
}

// MFMA implicit-GEMM conv — R7's plane-major 512-thr version, VERBATIM
// (133.6 µs anchor; R8's swizzle experiment reverted: the global-source
// permutation broke DMA coalescing and the read-side XOR broke ds_read
// offset folding, net +14.5 µs — and proved the linear pattern was not
// meaningfully bank-conflicted). Each A-fragment ds_read ONCE, used by 3
// MFMAs (kd=0,1,2 -> 3 rotating acc sets). 2-slot LDS double buffer
// (21,760 B), staging via global_load_lds, one __syncthreads per plane.
// 8 waves, 2 q-subtiles/wave. OOB halo lanes load a zeroed dummy region.
// k5 folded in: block (0,0,0) writes the 21 hist outputs.
#define DT 8
#define PLANE 5440          // 10*34*16 ushorts = 10,880 B per plane slot
__global__ __launch_bounds__(512, 4) void k4_conv(const unsigned short* __restrict__ z,
                                                  const unsigned short* __restrict__ fbw2,
                                                  const char* __restrict__ dummyc,
                                                  const int* __restrict__ hist,
                                                  float* __restrict__ out) {
  __shared__ unsigned short lz[2 * PLANE];   // 21,760 B
  const int t = threadIdx.x;
  if (blockIdx.x == 0 && blockIdx.y == 0 && blockIdx.z == 0 && t < 21)
    out[33554432u + t] = (float)hist[t] * (100.0f / 33554432.0f);
  const int lane = t & 63, wid = t >> 6;     // 8 waves
  const int b = blockIdx.z;
  const int d0 = blockIdx.y * DT;
  const int h0 = (blockIdx.x >> 2) * 8, w0 = (blockIdx.x & 3) * 32;
  const int m = lane & 15, g = lane >> 4;
  const int icb = (g & 1) * 8, g2 = g >> 1;

  // weights: 15 B-fragments (kd*5 + c), register-resident (60 VGPR)
  short8 fb2[15];
  #pragma unroll
  for (int f = 0; f < 15; ++f)
    fb2[f] = *(const short8*)(fbw2 + (f * 64 + lane) * 8);

  // per-lane A-read tap offsets (ushort units) for c = 0..4
  int tco[5];
  #pragma unroll
  for (int c = 0; c < 5; ++c) {
    int tap = 2 * c + g2; if (tap > 8) tap = 8;
    tco[c] = ((tap / 3) * 34 + (tap % 3)) * 16;
  }

  const char* zbc = (const char*)(z + (size_t)b * 16777216);   // bytes base

  // staging: 680 granules/plane. chunk A: granule = t (waves 0-7, 512).
  // chunk B: wid0 -> 512+, wid1 -> 576+, wid2 -> 616+ (616-639 double-written
  // with identical data); waves 3-7 idle on chunk B.
  const int cbA = wid * 64;
  const int cbB = (wid == 0) ? 512 : (wid == 1) ? 576 : 616;
  const bool hasB = (wid < 3);
  long long hobA, hobB; bool hvA, hvB;
  {
    int gi, r, rem, s, ig, hg, wg;
    gi = cbA + lane; r = gi / 68; rem = gi - r * 68; s = rem >> 1; ig = rem & 1;
    hg = h0 - 1 + r; wg = w0 - 1 + s;
    hvA = ((unsigned)hg < 128u) && ((unsigned)wg < 128u);
    hobA = ((long long)(hg * 128 + wg) * 16 + ig * 8) * 2;
    gi = cbB + lane; r = gi / 68; rem = gi - r * 68; s = rem >> 1; ig = rem & 1;
    hg = h0 - 1 + r; wg = w0 - 1 + s;
    hvB = ((unsigned)hg < 128u) && ((unsigned)wg < 128u);
    hobB = ((long long)(hg * 128 + wg) * 16 + ig * 8) * 2;
  }

  const f32x4 fzero = {0.f, 0.f, 0.f, 0.f};
  f32x4 A0[2], A1[2], A2[2];
  #pragma unroll
  for (int q = 0; q < 2; ++q) { A0[q] = fzero; A1[q] = fzero; A2[q] = fzero; }

  // prologue: stage plane 0 (global d = d0-1) into slot 0
  {
    const int dg = d0 - 1;
    const long long dgo = (long long)dg * 524288;
    const bool pd = (unsigned)dg < 64u;
    gload_lds16((pd && hvA) ? zbc + dgo + hobA : dummyc, &lz[cbA * 8]);
    if (hasB)
      gload_lds16((pd && hvB) ? zbc + dgo + hobB : dummyc, &lz[cbB * 8]);
  }
  __syncthreads();

  // BODY(ph): issue loads for plane ph+1 -> slot (ph+1)&1; compute plane ph
  // from slot ph&1 (j2 -> AN [kd=0], j1 -> AM [kd=1], j0 -> AS [kd=2]);
  // store AS (dout = d0+ph-2); barrier.
#define BODY(PH, AS, AM, AN, DOJ2, DOJ1, DOJ0, DOLOAD, DOSTORE)                         \
  {                                                                                     \
    const int ph_ = (PH);                                                               \
    if (DOLOAD) {                                                                       \
      const int dg = d0 + ph_;                                                          \
      const long long dgo = (long long)dg * 524288;                                     \
      const bool pd = (unsigned)dg < 64u;                                               \
      const unsigned sl = ((unsigned)(ph_ + 1) & 1u) * PLANE;                           \
      gload_lds16((pd && hvA) ? zbc + dgo + hobA : dummyc, &lz[sl + cbA * 8]);          \
      if (hasB)                                                                         \
        gload_lds16((pd && hvB) ? zbc + dgo + hobB : dummyc, &lz[sl + cbB * 8]);        \
    }                                                                                   \
    const unsigned su = ((unsigned)ph_ & 1u) * PLANE;                                   \
    __builtin_amdgcn_s_setprio(1);                                                      \
    _Pragma("unroll")                                                                   \
    for (int q = 0; q < 2; ++q) {                                                       \
      const int hl = wid, wt = q;                                                       \
      const int qb = (hl * 34 + wt * 16 + m) * 16 + icb + (int)su;                      \
      _Pragma("unroll")                                                                 \
      for (int c = 0; c < 5; ++c) {                                                     \
        short8 a = *(const short8*)(&lz[qb + tco[c]]);                                  \
        if (DOJ2) AN[q] = __builtin_amdgcn_mfma_f32_16x16x32_bf16(a, fb2[c], AN[q], 0, 0, 0);      \
        if (DOJ1) AM[q] = __builtin_amdgcn_mfma_f32_16x16x32_bf16(a, fb2[5 + c], AM[q], 0, 0, 0);  \
        if (DOJ0) AS[q] = __builtin_amdgcn_mfma_f32_16x16x32_bf16(a, fb2[10 + c], AS[q], 0, 0, 0); \
      }                                                                                 \
    }                                                                                   \
    __builtin_amdgcn_s_setprio(0);                                                      \
    if (DOSTORE) {                                                                      \
      const int dd = d0 + ph_ - 2;                                                      \
      _Pragma("unroll")                                                                 \
      for (int q = 0; q < 2; ++q) {                                                     \
        const int hl = wid, wt = q;                                                     \
        float* op = out + (((size_t)(b * 16 + m) * 64 + dd) * 128 + (h0 + hl)) * 128    \
                    + w0 + wt * 16 + g * 4;                                             \
        *(float4*)op = make_float4(AS[q][0], AS[q][1], AS[q][2], AS[q][3]);             \
        AS[q] = fzero;                                                                  \
      }                                                                                 \
    }                                                                                   \
    __syncthreads();                                                                    \
  }

  // peel: planes 0,1 skip j's that would target out-of-block depths
  BODY(0, A1, A2, A0, 1, 0, 0, 1, 0)
  BODY(1, A2, A0, A1, 1, 1, 0, 1, 0)
  BODY(2, A0, A1, A2, 1, 1, 1, 1, 1)
  #pragma unroll 1
  for (int pp = 3; pp <= 6; pp += 3) {
    BODY(pp,     A1, A2, A0, 1, 1, 1, 1, 1)
    BODY(pp + 1, A2, A0, A1, 1, 1, 1, 1, 1)
    BODY(pp + 2, A0, A1, A2, 1, 1, 1, 1, 1)
  }
  // tail: plane 9 only finishes dout d0+7 (j0); no further loads
  BODY(9, A1, A2, A0, 0, 0, 1, 0, 1)
#undef BODY
}

extern "C" void kernel_launch(void* const* d_in, const int* in_sizes, int n_in,
                              void* d_out, int out_size, void* d_ws, size_t ws_size,
                              hipStream_t stream) {
  (void)in_sizes; (void)n_in; (void)out_size; (void)ws_size;
  const float* x   = (const float*)d_in[0];
  const float* gw  = (const float*)d_in[1];
  const float* gb  = (const float*)d_in[2];
  const float* thr = (const float*)d_in[3];
  const float* cw  = (const float*)d_in[4];
  float* out = (float*)d_out;

  char* ws = (char*)d_ws;
  unsigned short* z = (unsigned short*)ws;                               // 64 MiB bf16
  float2* partials  = (float2*)(ws + (size_t)67108864);                  // 8 KiB
  float2* stats     = (float2*)(ws + (size_t)67108864 + 8192);           // 128 B
  int*    hist      = (int*)  (ws + (size_t)67108864 + 8192 + 128);      // 84 B
  unsigned int* dummy = (unsigned int*)(ws + (size_t)67108864 + 8448);   // 64 B zeros
  unsigned short* fbw2 = (unsigned short*)(ws + (size_t)67108864 + 16384); // 15,360 B

  k1_partials<<<1024, 256, 0, stream>>>(x, partials);
  k2_prep<<<1, 1024, 0, stream>>>(partials, cw, stats, hist, fbw2, dummy);
  k3_norm_thresh_hist<<<1024, 256, 0, stream>>>(x, gw, gb, thr, stats, z, hist);
  k4_conv<<<dim3(64, 8, 2), 512, 0, stream>>>(z, fbw2, (const char*)dummy, hist, out);
}

// Round 10
// 122.474 us; speedup vs baseline: 1.2092x; 1.0905x over previous
//
#include <hip/hip_runtime.h>

typedef __attribute__((ext_vector_type(8))) short short8;
typedef __attribute__((ext_vector_type(4))) float f32x4;

#define GROUP_ELEMS 2097152     // 2 channels * 64*128*128
#define NBLK 64

__device__ inline short f2bf(float f) {
  unsigned u = __builtin_bit_cast(unsigned, f);
  unsigned r = (u + 0x7FFFu + ((u >> 16) & 1u)) >> 16;
  return (short)r;
}

__device__ inline void gload_lds16(const void* g, void* l) {
  __builtin_amdgcn_global_load_lds(
      (const __attribute__((address_space(1))) unsigned int*)g,
      (__attribute__((address_space(3))) unsigned int*)l, 16, 0, 0);
}

// k1: per-block group partial sums (blocks 0..1023) + prep work folded into
// block 1024 (conv-weight repack, hist zero, dummy zero — none of it depends
// on the partials, so it rides along and the former k2 launch disappears).
__global__ __launch_bounds__(256) void k1_partials(const float* __restrict__ x,
                                                   float2* __restrict__ partials,
                                                   const float* __restrict__ wgt,
                                                   unsigned short* __restrict__ fbw2,
                                                   int* __restrict__ hist,
                                                   unsigned int* __restrict__ dummy) {
  if (blockIdx.x == 1024) {
    int t0 = threadIdx.x;
    if (t0 < 21) hist[t0] = 0;
    #pragma unroll
    for (int it = 0; it < 4; ++it) {
      int t = t0 + it * 256;
      if (t < 960) {
        int f = t >> 6, lane = t & 63;
        int kd = f / 5, c = f - kd * 5;
        int m = lane & 15, g = lane >> 4;
        int icb = (g & 1) * 8, g2 = g >> 1;
        int tap = 2 * c + g2;          // 0..9
        short8 v;
        #pragma unroll
        for (int j = 0; j < 8; ++j)
          v[j] = (tap <= 8) ? f2bf(wgt[m * 432 + (icb + j) * 27 + kd * 9 + tap]) : (short)0;
        *(short8*)(fbw2 + t * 8) = v;
      }
      if (t >= 960 && t < 976) dummy[t - 960] = 0;
    }
    return;
  }
  int group = blockIdx.x >> 6;
  int blk = blockIdx.x & 63;
  const float4* p = (const float4*)(x + (size_t)group * GROUP_ELEMS + (size_t)blk * 32768);
  float sum = 0.f, sq = 0.f;
  for (int i = threadIdx.x; i < 8192; i += 256) {
    float4 v = p[i];
    sum += v.x + v.y + v.z + v.w;
    sq  += v.x*v.x + v.y*v.y + v.z*v.z + v.w*v.w;
  }
  for (int off = 32; off; off >>= 1) {
    sum += __shfl_down(sum, off, 64);
    sq  += __shfl_down(sq,  off, 64);
  }
  __shared__ float2 sw[4];
  int lane = threadIdx.x & 63, wid = threadIdx.x >> 6;
  if (lane == 0) sw[wid] = make_float2(sum, sq);
  __syncthreads();
  if (threadIdx.x == 0) {
    float s = 0.f, q = 0.f;
    for (int j = 0; j < 4; ++j) { s += sw[j].x; q += sw[j].y; }
    partials[blockIdx.x] = make_float2(s, q);
  }
}

// GroupNorm+ReLU+hist+threshold. Changes vs R9:
// (a) stats computed INLINE per block from the 8-KB partials (two-level LDS
//     reduction, L2/L3-hot) — the single-block k2 launch is gone.
// (b) z-store via LDS full-line assembly: the old per-thread store wrote 8 B
//     per 32-B sector (16 cache lines per wave-instr = 4x L2 write-transaction
//     amplification on a 64-MB stream — k3's real limiter; VALU cuts were
//     null in R9). Now each thread drops its packed dword into sd[2][256]
//     (bank-rotated: +4*row, <=2 lanes/bank on both access patterns), one
//     barrier, then stores sd[perm(t)] to the LINEAR dword zbase+d*131072+t:
//     256 thr = 1 KB contiguous, 4 transactions/wave. Double buffer -> one
//     barrier per d.
__global__ __launch_bounds__(256) void k3_norm_thresh_hist(
    const float* __restrict__ x, const float* __restrict__ gw, const float* __restrict__ gb,
    const float* __restrict__ thrp, const float2* __restrict__ partials,
    unsigned short* __restrict__ z, int* __restrict__ hist) {
  __shared__ int sh[21];
  __shared__ float4 stf[8];        // (A0,B0,A1,B1) per cp
  __shared__ float red[64], redq[64];
  __shared__ unsigned sd[2][256];
  int t = threadIdx.x;
  if (t < 21) sh[t] = 0;
  int b = blockIdx.x >> 9;
  if (t < 64) {                    // 8 groups x 8 threads, 8 partials each
    int gloc = t >> 3, j8 = t & 7;
    const float2* pp = partials + (b * 8 + gloc) * NBLK + j8 * 8;
    float s = 0.f, q = 0.f;
    #pragma unroll
    for (int k = 0; k < 8; ++k) { float2 pv = pp[k]; s += pv.x; q += pv.y; }
    red[t] = s; redq[t] = q;
  }
  __syncthreads();
  if (t < 8) {
    float s = 0.f, q = 0.f;
    #pragma unroll
    for (int k = 0; k < 8; ++k) { s += red[t * 8 + k]; q += redq[t * 8 + k]; }
    float mean = s / (float)GROUP_ELEMS;
    float var  = q / (float)GROUP_ELEMS - mean * mean;
    float rs = rsqrtf(var + 1e-5f);
    int c0 = t * 2;
    float A0 = gw[c0] * rs,     B0 = gb[c0] - mean * A0;
    float A1 = gw[c0 + 1] * rs, B1 = gb[c0 + 1] - mean * A1;
    stf[t] = make_float4(A0, B0, A1, B1);
  }
  __syncthreads();
  int hwl = t & 31, cp = t >> 5;
  int hw0 = (blockIdx.x & 511) * 32;
  int hw = hw0 + hwl;
  float4 st = stf[cp];
  float A0 = st.x, B0 = st.y, A1 = st.z, B1 = st.w;
  float thr = thrp[0];
  int c0 = cp * 2, c1 = c0 + 1;
  const float* px0 = x + (size_t)(b * 16 + c0) * 1048576 + hw;
  const float* px1 = x + (size_t)(b * 16 + c1) * 1048576 + hw;
  unsigned* zout = (unsigned*)z;
  const unsigned zbase = (unsigned)(b * 1048576 + hw0) * 8;
  const int wi = (cp << 5) | ((hwl + 4 * cp) & 31);
  const int ri = ((t & 7) << 5) | (((t >> 3) + 4 * (t & 7)) & 31);
  int c10 = 0, c11 = 0, c12 = 0;
  float xv0 = px0[0], xv1 = px1[0];
  float xm0 = px0[16384], xm1 = px1[16384];
  float yp0 = 0.f, yp1 = 0.f;
  for (int d = 0; d < 64; ++d) {
    float n0 = 0.f, n1 = 0.f;
    if (d < 62) { n0 = px0[(d + 2) * 16384]; n1 = px1[(d + 2) * 16384]; }
    float y0 = fmaxf(fmaf(xv0, A0, B0), 0.f);
    float y1 = fmaxf(fmaf(xv1, A1, B1), 0.f);
    float v0 = ceilf(0.5f * y0);
    if (v0 == 0.f) c10++; else if (v0 == 1.f) c11++; else if (v0 == 2.f) c12++;
    else if (v0 <= 10.f) atomicAdd(&sh[(int)v0 + 10], 1);
    float v1 = ceilf(0.5f * y1);
    if (v1 == 0.f) c10++; else if (v1 == 1.f) c11++; else if (v1 == 2.f) c12++;
    else if (v1 <= 10.f) atomicAdd(&sh[(int)v1 + 10], 1);
    float z0, z1;
    if (d == 0) { z0 = y0; z1 = y1; }
    else {
      z0 = (fabsf(y0 - yp0) > thr) ? y0 : yp0;
      z1 = (fabsf(y1 - yp1) > thr) ? y1 : yp1;
    }
    unsigned u = (unsigned)(unsigned short)f2bf(z0) | ((unsigned)(unsigned short)f2bf(z1) << 16);
    sd[d & 1][wi] = u;
    __syncthreads();
    zout[zbase + d * 131072 + t] = sd[d & 1][ri];
    yp0 = y0; yp1 = y1;
    xv0 = xm0; xv1 = xm1;
    xm0 = n0; xm1 = n1;
  }
  atomicAdd(&sh[10], c10);
  atomicAdd(&sh[11], c11);
  atomicAdd(&sh[12], c12);
  __syncthreads();
  if (t < 21) atomicAdd(&hist[t], sh[t]);
}

// MFMA implicit-GEMM conv — R7's plane-major 512-thr version, VERBATIM
// (133.6 µs anchor). Each A-fragment ds_read ONCE, used by 3 MFMAs
// (kd=0,1,2 -> 3 rotating acc sets). 2-slot LDS double buffer (21,760 B),
// staging via global_load_lds, one __syncthreads per plane. 8 waves,
// 2 q-subtiles/wave. OOB halo lanes load a zeroed dummy region.
// Block (0,0,0) writes the 21 hist outputs.
#define DT 8
#define PLANE 5440          // 10*34*16 ushorts = 10,880 B per plane slot
__global__ __launch_bounds__(512, 4) void k4_conv(const unsigned short* __restrict__ z,
                                                  const unsigned short* __restrict__ fbw2,
                                                  const char* __restrict__ dummyc,
                                                  const int* __restrict__ hist,
                                                  float* __restrict__ out) {
  __shared__ unsigned short lz[2 * PLANE];   // 21,760 B
  const int t = threadIdx.x;
  if (blockIdx.x == 0 && blockIdx.y == 0 && blockIdx.z == 0 && t < 21)
    out[33554432u + t] = (float)hist[t] * (100.0f / 33554432.0f);
  const int lane = t & 63, wid = t >> 6;     // 8 waves
  const int b = blockIdx.z;
  const int d0 = blockIdx.y * DT;
  const int h0 = (blockIdx.x >> 2) * 8, w0 = (blockIdx.x & 3) * 32;
  const int m = lane & 15, g = lane >> 4;
  const int icb = (g & 1) * 8, g2 = g >> 1;

  // weights: 15 B-fragments (kd*5 + c), register-resident (60 VGPR)
  short8 fb2[15];
  #pragma unroll
  for (int f = 0; f < 15; ++f)
    fb2[f] = *(const short8*)(fbw2 + (f * 64 + lane) * 8);

  // per-lane A-read tap offsets (ushort units) for c = 0..4
  int tco[5];
  #pragma unroll
  for (int c = 0; c < 5; ++c) {
    int tap = 2 * c + g2; if (tap > 8) tap = 8;
    tco[c] = ((tap / 3) * 34 + (tap % 3)) * 16;
  }

  const char* zbc = (const char*)(z + (size_t)b * 16777216);   // bytes base

  // staging: 680 granules/plane. chunk A: granule = t (waves 0-7, 512).
  // chunk B: wid0 -> 512+, wid1 -> 576+, wid2 -> 616+ (616-639 double-written
  // with identical data); waves 3-7 idle on chunk B.
  const int cbA = wid * 64;
  const int cbB = (wid == 0) ? 512 : (wid == 1) ? 576 : 616;
  const bool hasB = (wid < 3);
  long long hobA, hobB; bool hvA, hvB;
  {
    int gi, r, rem, s, ig, hg, wg;
    gi = cbA + lane; r = gi / 68; rem = gi - r * 68; s = rem >> 1; ig = rem & 1;
    hg = h0 - 1 + r; wg = w0 - 1 + s;
    hvA = ((unsigned)hg < 128u) && ((unsigned)wg < 128u);
    hobA = ((long long)(hg * 128 + wg) * 16 + ig * 8) * 2;
    gi = cbB + lane; r = gi / 68; rem = gi - r * 68; s = rem >> 1; ig = rem & 1;
    hg = h0 - 1 + r; wg = w0 - 1 + s;
    hvB = ((unsigned)hg < 128u) && ((unsigned)wg < 128u);
    hobB = ((long long)(hg * 128 + wg) * 16 + ig * 8) * 2;
  }

  const f32x4 fzero = {0.f, 0.f, 0.f, 0.f};
  f32x4 A0[2], A1[2], A2[2];
  #pragma unroll
  for (int q = 0; q < 2; ++q) { A0[q] = fzero; A1[q] = fzero; A2[q] = fzero; }

  // prologue: stage plane 0 (global d = d0-1) into slot 0
  {
    const int dg = d0 - 1;
    const long long dgo = (long long)dg * 524288;
    const bool pd = (unsigned)dg < 64u;
    gload_lds16((pd && hvA) ? zbc + dgo + hobA : dummyc, &lz[cbA * 8]);
    if (hasB)
      gload_lds16((pd && hvB) ? zbc + dgo + hobB : dummyc, &lz[cbB * 8]);
  }
  __syncthreads();

  // BODY(ph): issue loads for plane ph+1 -> slot (ph+1)&1; compute plane ph
  // from slot ph&1 (j2 -> AN [kd=0], j1 -> AM [kd=1], j0 -> AS [kd=2]);
  // store AS (dout = d0+ph-2); barrier.
#define BODY(PH, AS, AM, AN, DOJ2, DOJ1, DOJ0, DOLOAD, DOSTORE)                         \
  {                                                                                     \
    const int ph_ = (PH);                                                               \
    if (DOLOAD) {                                                                       \
      const int dg = d0 + ph_;                                                          \
      const long long dgo = (long long)dg * 524288;                                     \
      const bool pd = (unsigned)dg < 64u;                                               \
      const unsigned sl = ((unsigned)(ph_ + 1) & 1u) * PLANE;                           \
      gload_lds16((pd && hvA) ? zbc + dgo + hobA : dummyc, &lz[sl + cbA * 8]);          \
      if (hasB)                                                                         \
        gload_lds16((pd && hvB) ? zbc + dgo + hobB : dummyc, &lz[sl + cbB * 8]);        \
    }                                                                                   \
    const unsigned su = ((unsigned)ph_ & 1u) * PLANE;                                   \
    __builtin_amdgcn_s_setprio(1);                                                      \
    _Pragma("unroll")                                                                   \
    for (int q = 0; q < 2; ++q) {                                                       \
      const int hl = wid, wt = q;                                                       \
      const int qb = (hl * 34 + wt * 16 + m) * 16 + icb + (int)su;                      \
      _Pragma("unroll")                                                                 \
      for (int c = 0; c < 5; ++c) {                                                     \
        short8 a = *(const short8*)(&lz[qb + tco[c]]);                                  \
        if (DOJ2) AN[q] = __builtin_amdgcn_mfma_f32_16x16x32_bf16(a, fb2[c], AN[q], 0, 0, 0);      \
        if (DOJ1) AM[q] = __builtin_amdgcn_mfma_f32_16x16x32_bf16(a, fb2[5 + c], AM[q], 0, 0, 0);  \
        if (DOJ0) AS[q] = __builtin_amdgcn_mfma_f32_16x16x32_bf16(a, fb2[10 + c], AS[q], 0, 0, 0); \
      }                                                                                 \
    }                                                                                   \
    __builtin_amdgcn_s_setprio(0);                                                      \
    if (DOSTORE) {                                                                      \
      const int dd = d0 + ph_ - 2;                                                      \
      _Pragma("unroll")                                                                 \
      for (int q = 0; q < 2; ++q) {                                                     \
        const int hl = wid, wt = q;                                                     \
        float* op = out + (((size_t)(b * 16 + m) * 64 + dd) * 128 + (h0 + hl)) * 128    \
                    + w0 + wt * 16 + g * 4;                                             \
        *(float4*)op = make_float4(AS[q][0], AS[q][1], AS[q][2], AS[q][3]);             \
        AS[q] = fzero;                                                                  \
      }                                                                                 \
    }                                                                                   \
    __syncthreads();                                                                    \
  }

  // peel: planes 0,1 skip j's that would target out-of-block depths
  BODY(0, A1, A2, A0, 1, 0, 0, 1, 0)
  BODY(1, A2, A0, A1, 1, 1, 0, 1, 0)
  BODY(2, A0, A1, A2, 1, 1, 1, 1, 1)
  #pragma unroll 1
  for (int pp = 3; pp <= 6; pp += 3) {
    BODY(pp,     A1, A2, A0, 1, 1, 1, 1, 1)
    BODY(pp + 1, A2, A0, A1, 1, 1, 1, 1, 1)
    BODY(pp + 2, A0, A1, A2, 1, 1, 1, 1, 1)
  }
  // tail: plane 9 only finishes dout d0+7 (j0); no further loads
  BODY(9, A1, A2, A0, 0, 0, 1, 0, 1)
#undef BODY
}

extern "C" void kernel_launch(void* const* d_in, const int* in_sizes, int n_in,
                              void* d_out, int out_size, void* d_ws, size_t ws_size,
                              hipStream_t stream) {
  (void)in_sizes; (void)n_in; (void)out_size; (void)ws_size;
  const float* x   = (const float*)d_in[0];
  const float* gw  = (const float*)d_in[1];
  const float* gb  = (const float*)d_in[2];
  const float* thr = (const float*)d_in[3];
  const float* cw  = (const float*)d_in[4];
  float* out = (float*)d_out;

  char* ws = (char*)d_ws;
  unsigned short* z = (unsigned short*)ws;                               // 64 MiB bf16
  float2* partials  = (float2*)(ws + (size_t)67108864);                  // 8 KiB
  int*    hist      = (int*)  (ws + (size_t)67108864 + 8192 + 128);      // 84 B
  unsigned int* dummy = (unsigned int*)(ws + (size_t)67108864 + 8448);   // 64 B zeros
  unsigned short* fbw2 = (unsigned short*)(ws + (size_t)67108864 + 16384); // 15,360 B

  k1_partials<<<1025, 256, 0, stream>>>(x, partials, cw, fbw2, hist, dummy);
  k3_norm_thresh_hist<<<1024, 256, 0, stream>>>(x, gw, gb, thr, partials, z, hist);
  k4_conv<<<dim3(64, 8, 2), 512, 0, stream>>>(z, fbw2, (const char*)dummy, hist, out);
}

// Round 11
// 120.225 us; speedup vs baseline: 1.2318x; 1.0187x over previous
//
#include <hip/hip_runtime.h>

typedef __attribute__((ext_vector_type(8))) short short8;
typedef __attribute__((ext_vector_type(4))) float f32x4;

#define GROUP_ELEMS 2097152     // 2 channels * 64*128*128
#define NBLK 64

__device__ inline short f2bf(float f) {
  unsigned u = __builtin_bit_cast(unsigned, f);
  unsigned r = (u + 0x7FFFu + ((u >> 16) & 1u)) >> 16;
  return (short)r;
}

__device__ inline void gload_lds16(const void* g, void* l) {
  __builtin_amdgcn_global_load_lds(
      (const __attribute__((address_space(1))) unsigned int*)g,
      (__attribute__((address_space(3))) unsigned int*)l, 16, 0, 0);
}

// k1: per-block group partial sums (blocks 0..1023) + prep work folded into
// block 1024 (conv-weight repack, hist zero, dummy zero).
__global__ __launch_bounds__(256) void k1_partials(const float* __restrict__ x,
                                                   float2* __restrict__ partials,
                                                   const float* __restrict__ wgt,
                                                   unsigned short* __restrict__ fbw2,
                                                   int* __restrict__ hist,
                                                   unsigned int* __restrict__ dummy) {
  if (blockIdx.x == 1024) {
    int t0 = threadIdx.x;
    if (t0 < 21) hist[t0] = 0;
    #pragma unroll
    for (int it = 0; it < 4; ++it) {
      int t = t0 + it * 256;
      if (t < 960) {
        int f = t >> 6, lane = t & 63;
        int kd = f / 5, c = f - kd * 5;
        int m = lane & 15, g = lane >> 4;
        int icb = (g & 1) * 8, g2 = g >> 1;
        int tap = 2 * c + g2;          // 0..9
        short8 v;
        #pragma unroll
        for (int j = 0; j < 8; ++j)
          v[j] = (tap <= 8) ? f2bf(wgt[m * 432 + (icb + j) * 27 + kd * 9 + tap]) : (short)0;
        *(short8*)(fbw2 + t * 8) = v;
      }
      if (t >= 960 && t < 976) dummy[t - 960] = 0;
    }
    return;
  }
  int group = blockIdx.x >> 6;
  int blk = blockIdx.x & 63;
  const float4* p = (const float4*)(x + (size_t)group * GROUP_ELEMS + (size_t)blk * 32768);
  float sum = 0.f, sq = 0.f;
  for (int i = threadIdx.x; i < 8192; i += 256) {
    float4 v = p[i];
    sum += v.x + v.y + v.z + v.w;
    sq  += v.x*v.x + v.y*v.y + v.z*v.z + v.w*v.w;
  }
  for (int off = 32; off; off >>= 1) {
    sum += __shfl_down(sum, off, 64);
    sq  += __shfl_down(sq,  off, 64);
  }
  __shared__ float2 sw[4];
  int lane = threadIdx.x & 63, wid = threadIdx.x >> 6;
  if (lane == 0) sw[wid] = make_float2(sum, sq);
  __syncthreads();
  if (threadIdx.x == 0) {
    float s = 0.f, q = 0.f;
    for (int j = 0; j < 4; ++j) { s += sw[j].x; q += sw[j].y; }
    partials[blockIdx.x] = make_float2(s, q);
  }
}

// GroupNorm+ReLU+hist+threshold — R10 version verbatim (inline stats + LDS
// full-line z-store assembly; proven −11 µs).
__global__ __launch_bounds__(256) void k3_norm_thresh_hist(
    const float* __restrict__ x, const float* __restrict__ gw, const float* __restrict__ gb,
    const float* __restrict__ thrp, const float2* __restrict__ partials,
    unsigned short* __restrict__ z, int* __restrict__ hist) {
  __shared__ int sh[21];
  __shared__ float4 stf[8];        // (A0,B0,A1,B1) per cp
  __shared__ float red[64], redq[64];
  __shared__ unsigned sd[2][256];
  int t = threadIdx.x;
  if (t < 21) sh[t] = 0;
  int b = blockIdx.x >> 9;
  if (t < 64) {                    // 8 groups x 8 threads, 8 partials each
    int gloc = t >> 3, j8 = t & 7;
    const float2* pp = partials + (b * 8 + gloc) * NBLK + j8 * 8;
    float s = 0.f, q = 0.f;
    #pragma unroll
    for (int k = 0; k < 8; ++k) { float2 pv = pp[k]; s += pv.x; q += pv.y; }
    red[t] = s; redq[t] = q;
  }
  __syncthreads();
  if (t < 8) {
    float s = 0.f, q = 0.f;
    #pragma unroll
    for (int k = 0; k < 8; ++k) { s += red[t * 8 + k]; q += redq[t * 8 + k]; }
    float mean = s / (float)GROUP_ELEMS;
    float var  = q / (float)GROUP_ELEMS - mean * mean;
    float rs = rsqrtf(var + 1e-5f);
    int c0 = t * 2;
    float A0 = gw[c0] * rs,     B0 = gb[c0] - mean * A0;
    float A1 = gw[c0 + 1] * rs, B1 = gb[c0 + 1] - mean * A1;
    stf[t] = make_float4(A0, B0, A1, B1);
  }
  __syncthreads();
  int hwl = t & 31, cp = t >> 5;
  int hw0 = (blockIdx.x & 511) * 32;
  int hw = hw0 + hwl;
  float4 st = stf[cp];
  float A0 = st.x, B0 = st.y, A1 = st.z, B1 = st.w;
  float thr = thrp[0];
  int c0 = cp * 2, c1 = c0 + 1;
  const float* px0 = x + (size_t)(b * 16 + c0) * 1048576 + hw;
  const float* px1 = x + (size_t)(b * 16 + c1) * 1048576 + hw;
  unsigned* zout = (unsigned*)z;
  const unsigned zbase = (unsigned)(b * 1048576 + hw0) * 8;
  const int wi = (cp << 5) | ((hwl + 4 * cp) & 31);
  const int ri = ((t & 7) << 5) | (((t >> 3) + 4 * (t & 7)) & 31);
  int c10 = 0, c11 = 0, c12 = 0;
  float xv0 = px0[0], xv1 = px1[0];
  float xm0 = px0[16384], xm1 = px1[16384];
  float yp0 = 0.f, yp1 = 0.f;
  for (int d = 0; d < 64; ++d) {
    float n0 = 0.f, n1 = 0.f;
    if (d < 62) { n0 = px0[(d + 2) * 16384]; n1 = px1[(d + 2) * 16384]; }
    float y0 = fmaxf(fmaf(xv0, A0, B0), 0.f);
    float y1 = fmaxf(fmaf(xv1, A1, B1), 0.f);
    float v0 = ceilf(0.5f * y0);
    if (v0 == 0.f) c10++; else if (v0 == 1.f) c11++; else if (v0 == 2.f) c12++;
    else if (v0 <= 10.f) atomicAdd(&sh[(int)v0 + 10], 1);
    float v1 = ceilf(0.5f * y1);
    if (v1 == 0.f) c10++; else if (v1 == 1.f) c11++; else if (v1 == 2.f) c12++;
    else if (v1 <= 10.f) atomicAdd(&sh[(int)v1 + 10], 1);
    float z0, z1;
    if (d == 0) { z0 = y0; z1 = y1; }
    else {
      z0 = (fabsf(y0 - yp0) > thr) ? y0 : yp0;
      z1 = (fabsf(y1 - yp1) > thr) ? y1 : yp1;
    }
    unsigned u = (unsigned)(unsigned short)f2bf(z0) | ((unsigned)(unsigned short)f2bf(z1) << 16);
    sd[d & 1][wi] = u;
    __syncthreads();
    zout[zbase + d * 131072 + t] = sd[d & 1][ri];
    yp0 = y0; yp1 = y1;
    xv0 = xm0; xv1 = xm1;
    xm0 = n0; xm1 = n1;
  }
  atomicAdd(&sh[10], c10);
  atomicAdd(&sh[11], c11);
  atomicAdd(&sh[12], c12);
  __syncthreads();
  if (t < 21) atomicAdd(&hist[t], sh[t]);
}

// MFMA implicit-GEMM conv, plane-major 512-thr, 2-PLANES-PER-BARRIER.
// k4's cycle model (MFMA ~2330 + LDS ~1920 + DMA ~2180 cyc per body-epoch)
// matched the SERIALIZED sum at 10 barriers/block: the __syncthreads vmcnt(0)
// drain serializes DMA against compute every plane. Fix (semantics-safe, no
// raw-barrier asm — R5 proved that path regresses): 4-slot LDS ring
// (43,520 B, still 2 blocks/CU — VGPR-bound), each epoch issues DMA for
// planes 2k+2,2k+3 (slots disjoint mod 4 from the 2 compute slots), computes
// planes 2k,2k+1, stores 2 douts, ONE __syncthreads. 10 -> 5 drains, and each
// DMA batch hides under 2 planes of compute. Per-plane math/flags identical.
#define DT 8
#define PLANE 5440          // 10*34*16 ushorts = 10,880 B per plane slot
__global__ __launch_bounds__(512, 4) void k4_conv(const unsigned short* __restrict__ z,
                                                  const unsigned short* __restrict__ fbw2,
                                                  const char* __restrict__ dummyc,
                                                  const int* __restrict__ hist,
                                                  float* __restrict__ out) {
  __shared__ unsigned short lz[4 * PLANE];   // 43,520 B
  const int t = threadIdx.x;
  if (blockIdx.x == 0 && blockIdx.y == 0 && blockIdx.z == 0 && t < 21)
    out[33554432u + t] = (float)hist[t] * (100.0f / 33554432.0f);
  const int lane = t & 63, wid = t >> 6;     // 8 waves
  const int b = blockIdx.z;
  const int d0 = blockIdx.y * DT;
  const int h0 = (blockIdx.x >> 2) * 8, w0 = (blockIdx.x & 3) * 32;
  const int m = lane & 15, g = lane >> 4;
  const int icb = (g & 1) * 8, g2 = g >> 1;

  // weights: 15 B-fragments (kd*5 + c), register-resident (60 VGPR)
  short8 fb2[15];
  #pragma unroll
  for (int f = 0; f < 15; ++f)
    fb2[f] = *(const short8*)(fbw2 + (f * 64 + lane) * 8);

  // per-lane A-read tap offsets (ushort units) for c = 0..4
  int tco[5];
  #pragma unroll
  for (int c = 0; c < 5; ++c) {
    int tap = 2 * c + g2; if (tap > 8) tap = 8;
    tco[c] = ((tap / 3) * 34 + (tap % 3)) * 16;
  }

  const char* zbc = (const char*)(z + (size_t)b * 16777216);   // bytes base

  // staging: 680 granules/plane. chunk A: granule = t (waves 0-7, 512).
  // chunk B: wid0 -> 512+, wid1 -> 576+, wid2 -> 616+ (616-639 double-written
  // with identical data); waves 3-7 idle on chunk B.
  const int cbA = wid * 64;
  const int cbB = (wid == 0) ? 512 : (wid == 1) ? 576 : 616;
  const bool hasB = (wid < 3);
  long long hobA, hobB; bool hvA, hvB;
  {
    int gi, r, rem, s, ig, hg, wg;
    gi = cbA + lane; r = gi / 68; rem = gi - r * 68; s = rem >> 1; ig = rem & 1;
    hg = h0 - 1 + r; wg = w0 - 1 + s;
    hvA = ((unsigned)hg < 128u) && ((unsigned)wg < 128u);
    hobA = ((long long)(hg * 128 + wg) * 16 + ig * 8) * 2;
    gi = cbB + lane; r = gi / 68; rem = gi - r * 68; s = rem >> 1; ig = rem & 1;
    hg = h0 - 1 + r; wg = w0 - 1 + s;
    hvB = ((unsigned)hg < 128u) && ((unsigned)wg < 128u);
    hobB = ((long long)(hg * 128 + wg) * 16 + ig * 8) * 2;
  }

  const f32x4 fzero = {0.f, 0.f, 0.f, 0.f};
  f32x4 A0[2], A1[2], A2[2];
  #pragma unroll
  for (int q = 0; q < 2; ++q) { A0[q] = fzero; A1[q] = fzero; A2[q] = fzero; }

  // STAGE(P): issue DMA for plane P (global d = d0-1+P) into slot P&3
#define STAGE(P)                                                                        \
  {                                                                                     \
    const int dg = d0 - 1 + (P);                                                        \
    const long long dgo = (long long)dg * 524288;                                       \
    const bool pd = (unsigned)dg < 64u;                                                 \
    const unsigned sl = ((unsigned)(P) & 3u) * PLANE;                                   \
    gload_lds16((pd && hvA) ? zbc + dgo + hobA : dummyc, &lz[sl + cbA * 8]);            \
    if (hasB)                                                                           \
      gload_lds16((pd && hvB) ? zbc + dgo + hobB : dummyc, &lz[sl + cbB * 8]);          \
  }

  // PC(P,...): compute plane P from slot P&3 (j2 -> AN [kd=0], j1 -> AM
  // [kd=1], j0 -> AS [kd=2]); optionally store AS (dout = d0+P-2).
#define PC(P, AS, AM, AN, DOJ2, DOJ1, DOJ0, DOSTORE)                                    \
  {                                                                                     \
    const unsigned su = ((unsigned)(P) & 3u) * PLANE;                                   \
    __builtin_amdgcn_s_setprio(1);                                                      \
    _Pragma("unroll")                                                                   \
    for (int q = 0; q < 2; ++q) {                                                       \
      const int hl = wid, wt = q;                                                       \
      const int qb = (hl * 34 + wt * 16 + m) * 16 + icb + (int)su;                      \
      _Pragma("unroll")                                                                 \
      for (int c = 0; c < 5; ++c) {                                                     \
        short8 a = *(const short8*)(&lz[qb + tco[c]]);                                  \
        if (DOJ2) AN[q] = __builtin_amdgcn_mfma_f32_16x16x32_bf16(a, fb2[c], AN[q], 0, 0, 0);      \
        if (DOJ1) AM[q] = __builtin_amdgcn_mfma_f32_16x16x32_bf16(a, fb2[5 + c], AM[q], 0, 0, 0);  \
        if (DOJ0) AS[q] = __builtin_amdgcn_mfma_f32_16x16x32_bf16(a, fb2[10 + c], AS[q], 0, 0, 0); \
      }                                                                                 \
    }                                                                                   \
    __builtin_amdgcn_s_setprio(0);                                                      \
    if (DOSTORE) {                                                                      \
      const int dd = d0 + (P) - 2;                                                      \
      _Pragma("unroll")                                                                 \
      for (int q = 0; q < 2; ++q) {                                                     \
        const int hl = wid, wt = q;                                                     \
        float* op = out + (((size_t)(b * 16 + m) * 64 + dd) * 128 + (h0 + hl)) * 128    \
                    + w0 + wt * 16 + g * 4;                                             \
        *(float4*)op = make_float4(AS[q][0], AS[q][1], AS[q][2], AS[q][3]);             \
        AS[q] = fzero;                                                                  \
      }                                                                                 \
    }                                                                                   \
  }

  // prologue: planes 0,1 -> slots 0,1
  STAGE(0) STAGE(1)
  __syncthreads();
  // epoch 0: DMA planes 2,3; compute planes 0 (j2), 1 (j2,j1); no stores
  STAGE(2) STAGE(3)
  PC(0, A1, A2, A0, 1, 0, 0, 0)
  PC(1, A2, A0, A1, 1, 1, 0, 0)
  __syncthreads();
  // epoch 1: DMA 4,5; compute 2,3; store douts d0+0, d0+1
  STAGE(4) STAGE(5)
  PC(2, A0, A1, A2, 1, 1, 1, 1)
  PC(3, A1, A2, A0, 1, 1, 1, 1)
  __syncthreads();
  // epoch 2: DMA 6,7; compute 4,5; store douts d0+2, d0+3
  STAGE(6) STAGE(7)
  PC(4, A2, A0, A1, 1, 1, 1, 1)
  PC(5, A0, A1, A2, 1, 1, 1, 1)
  __syncthreads();
  // epoch 3: DMA 8,9; compute 6,7; store douts d0+4, d0+5
  STAGE(8) STAGE(9)
  PC(6, A1, A2, A0, 1, 1, 1, 1)
  PC(7, A2, A0, A1, 1, 1, 1, 1)
  __syncthreads();
  // epoch 4: compute 8 (full), 9 (j0 only); store douts d0+6, d0+7
  PC(8, A0, A1, A2, 1, 1, 1, 1)
  PC(9, A1, A2, A0, 0, 0, 1, 1)
#undef STAGE
#undef PC
}

extern "C" void kernel_launch(void* const* d_in, const int* in_sizes, int n_in,
                              void* d_out, int out_size, void* d_ws, size_t ws_size,
                              hipStream_t stream) {
  (void)in_sizes; (void)n_in; (void)out_size; (void)ws_size;
  const float* x   = (const float*)d_in[0];
  const float* gw  = (const float*)d_in[1];
  const float* gb  = (const float*)d_in[2];
  const float* thr = (const float*)d_in[3];
  const float* cw  = (const float*)d_in[4];
  float* out = (float*)d_out;

  char* ws = (char*)d_ws;
  unsigned short* z = (unsigned short*)ws;                               // 64 MiB bf16
  float2* partials  = (float2*)(ws + (size_t)67108864);                  // 8 KiB
  int*    hist      = (int*)  (ws + (size_t)67108864 + 8192 + 128);      // 84 B
  unsigned int* dummy = (unsigned int*)(ws + (size_t)67108864 + 8448);   // 64 B zeros
  unsigned short* fbw2 = (unsigned short*)(ws + (size_t)67108864 + 16384); // 15,360 B

  k1_partials<<<1025, 256, 0, stream>>>(x, partials, cw, fbw2, hist, dummy);
  k3_norm_thresh_hist<<<1024, 256, 0, stream>>>(x, gw, gb, thr, partials, z, hist);
  k4_conv<<<dim3(64, 8, 2), 512, 0, stream>>>(z, fbw2, (const char*)dummy, hist, out);
}